// Round 5
// baseline (307.386 us; speedup 1.0000x reference)
//
#include <hip/hip_runtime.h>

#define B_ 16
#define D_ 64
#define T_ 4096
#define K_ 512
#define N_ (B_*T_)        // 65536 vectors
#define Q_ (B_*D_*T_)     // 4194304 quantized elements
#define ENC_OFF ((size_t)(2 + Q_))  // encodings start in d_out

// ws layout (bytes) — ~136 KB
#define WS_LOSS    0        // double
#define WS_TICKET  8        // int (last-block ticket)
#define WS_HIST    16       // int[512]
#define WS_NE      2064     // float[512]
#define WS_CBH     4608     // bf16x8[32*2*64]  (64 KB) codebook hi frags
#define WS_CBL     70144    // bf16x8[32*2*64]  (64 KB) codebook lo frags

typedef __bf16 bf16x8 __attribute__((ext_vector_type(8)));
typedef float  f32x4  __attribute__((ext_vector_type(4)));
typedef float  f32x2  __attribute__((ext_vector_type(2)));

// ---------------- K0: init + ne + codebook hi/lo B-fragments ----------------
// Grid = 16 blocks x 256 threads.
__global__ __launch_bounds__(256) void k0_init(const float* __restrict__ cb,
                                               float* __restrict__ ne,
                                               int* __restrict__ hist,
                                               double* __restrict__ loss,
                                               int* __restrict__ ticket,
                                               bf16x8* __restrict__ cbh,
                                               bf16x8* __restrict__ cbl) {
    int bidx = blockIdx.x, tid = threadIdx.x;

    // ne: 32 codes per block, 8 lanes per code
    {
        int code = bidx * 32 + (tid >> 3), sl = tid & 7;
        float s = 0.f;
#pragma unroll
        for (int j = 0; j < 8; ++j) { float c = cb[code * 64 + sl * 8 + j]; s = fmaf(c, c, s); }
        s += __shfl_xor(s, 1); s += __shfl_xor(s, 2); s += __shfl_xor(s, 4);
        if (sl == 0) ne[code] = s;
    }
    if (bidx == 0) {
        hist[tid] = 0; hist[tid + 256] = 0;
        if (tid == 0) { *loss = 0.0; *ticket = 0; }
    }

    // B-frag element (ct,ks,lane,j) = cb[ct*16 + (lane&15)][ks*32 + (lane>>4)*8 + j]
    int e = bidx * 256 + tid;
    int ct = e >> 7, ks = (e >> 6) & 1, lane = e & 63;
    int code  = ct * 16 + (lane & 15);
    int dbase = ks * 32 + ((lane >> 4) << 3);
    bf16x8 h, l;
#pragma unroll
    for (int j = 0; j < 8; ++j) {
        float v = cb[code * 64 + dbase + j];
        __bf16 hv = (__bf16)v;
        __bf16 lv = (__bf16)(v - (float)hv);
        h[j] = hv; l[j] = lv;
    }
    cbh[(ct * 2 + ks) * 64 + lane] = h;
    cbl[(ct * 2 + ks) * 64 + lane] = l;
}

// ---------------- K_MAIN: 32-row blocks, grid 2048, 8 blocks/CU -------------
// R4 diagnosis: latency-bound (MfmaUtil 4%, VALUBusy 7%, HBM 18%, occ 30%).
// Fix: double TLP. Block = 256 thr = 4 waves; wave w handles row-tile (w&1)
// [16 rows] x ct-half (w>>1) [16 codebook tiles]; cross-half argmin via LDS.
// Cached stores (nt regressed -35us in R4). Finalize folded (last-block ticket).
__global__ __launch_bounds__(256, 8) void k_main(const float* __restrict__ in,
                                                 const float* __restrict__ cb,
                                                 const bf16x8* __restrict__ cbh,
                                                 const bf16x8* __restrict__ cbl,
                                                 const float* __restrict__ ne,
                                                 float* __restrict__ out,
                                                 f32x2* __restrict__ enc2,
                                                 int* __restrict__ hist,
                                                 double* __restrict__ loss,
                                                 int* __restrict__ ticket) {
    __shared__ float X[64][33];      // dim-major: X[d][row_local], 8.4 KB
    __shared__ float ne_s[512];
    __shared__ float smin[2][32];
    __shared__ int   smid[2][32];
    __shared__ int   sidx[32];
    int tid = threadIdx.x;
    int n0 = blockIdx.x * 32;
    int b  = n0 >> 12, t0 = n0 & (T_ - 1);

    { // stage x-tile: 64 dims x 32 rows = 2048 floats; 2 float4 per thread
        int d = tid >> 2, c0 = (tid & 3) * 8;
        const float4* ip = (const float4*)(in + ((size_t)b * 64 + d) * T_ + t0 + c0);
        float4 v0 = ip[0], v1 = ip[1];
        X[d][c0 + 0] = v0.x; X[d][c0 + 1] = v0.y; X[d][c0 + 2] = v0.z; X[d][c0 + 3] = v0.w;
        X[d][c0 + 4] = v1.x; X[d][c0 + 5] = v1.y; X[d][c0 + 6] = v1.z; X[d][c0 + 7] = v1.w;
    }
    ne_s[tid] = ne[tid];
    ne_s[tid + 256] = ne[tid + 256];
    __syncthreads();

    int w = tid >> 6, lane = tid & 63;
    int col = lane & 15, q = lane >> 4;
    int rt = w & 1;          // row-tile (16 rows each)
    int ch = w >> 1;         // codebook half (16 ct tiles each)

    // A-frags for this wave's 16 rows: A[m][k=ks*32+q*8+j] = X[k][rt*16+col]
    bf16x8 Ah[2], Al[2];
#pragma unroll
    for (int ks = 0; ks < 2; ++ks) {
        bf16x8 h, l;
#pragma unroll
        for (int j = 0; j < 8; ++j) {
            float v = X[ks * 32 + q * 8 + j][rt * 16 + col];
            __bf16 hv = (__bf16)v;
            __bf16 lv = (__bf16)(v - (float)hv);
            h[j] = hv; l[j] = lv;
        }
        Ah[ks] = h; Al[ks] = l;
    }

    float m1[4]; int i1[4];
#pragma unroll
    for (int e = 0; e < 4; ++e) { m1[e] = 3.4e38f; i1[e] = 0; }

    for (int c16 = 0; c16 < 16; ++c16) {
        int ct = ch * 16 + c16;
        bf16x8 Bh0 = cbh[(ct * 2 + 0) * 64 + lane];
        bf16x8 Bh1 = cbh[(ct * 2 + 1) * 64 + lane];
        bf16x8 Bl0 = cbl[(ct * 2 + 0) * 64 + lane];
        bf16x8 Bl1 = cbl[(ct * 2 + 1) * 64 + lane];
        float nev = ne_s[ct * 16 + col];
        int code = ct * 16 + col;
        f32x4 acc = {0.f, 0.f, 0.f, 0.f};
        acc = __builtin_amdgcn_mfma_f32_16x16x32_bf16(Ah[0], Bh0, acc, 0, 0, 0);
        acc = __builtin_amdgcn_mfma_f32_16x16x32_bf16(Ah[1], Bh1, acc, 0, 0, 0);
        acc = __builtin_amdgcn_mfma_f32_16x16x32_bf16(Ah[0], Bl0, acc, 0, 0, 0);
        acc = __builtin_amdgcn_mfma_f32_16x16x32_bf16(Al[0], Bh0, acc, 0, 0, 0);
        acc = __builtin_amdgcn_mfma_f32_16x16x32_bf16(Ah[1], Bl1, acc, 0, 0, 0);
        acc = __builtin_amdgcn_mfma_f32_16x16x32_bf16(Al[1], Bh1, acc, 0, 0, 0);
        // lo*lo terms ~2^-32 relative: negligible, dropped
#pragma unroll
        for (int e = 0; e < 4; ++e) {
            float sc = fmaf(-2.f, acc[e], nev);   // ||e||^2 - 2 x.e
            bool lt = sc < m1[e];                 // strict: ties keep lowest code
            i1[e] = lt ? code : i1[e];
            m1[e] = lt ? sc : m1[e];
        }
    }

    // argmin across the 16 lanes (same q) holding this row's columns
#pragma unroll
    for (int e = 0; e < 4; ++e) {
        float a1 = m1[e]; int ai = i1[e];
#pragma unroll
        for (int off = 1; off < 16; off <<= 1) {
            float o1 = __shfl_xor(a1, off);
            int   oi = __shfl_xor(ai, off);
            bool tk = (o1 < a1) || (o1 == a1 && oi < ai);  // tie -> lower index
            a1 = tk ? o1 : a1; ai = tk ? oi : ai;
        }
        if (col == 0) { smin[ch][rt * 16 + q * 4 + e] = a1; smid[ch][rt * 16 + q * 4 + e] = ai; }
    }
    __syncthreads();

    // combine the two codebook halves (ch0 = codes 0..255 wins ties)
    if (tid < 32) {
        float a1 = smin[0][tid]; int ai = smid[0][tid];
        float o1 = smin[1][tid]; int oi = smid[1][tid];
        bool tk = (o1 < a1);                     // strict: tie -> lower code (ch0)
        sidx[tid] = tk ? oi : ai;
    }
    __syncthreads();

    // --- one-hot rows: 256 f32x2 cols per row, 32 rows (cached stores) ------
#pragma unroll 4
    for (int i = 0; i < 32; ++i) {
        int id = sidx[i];                      // uniform LDS read -> broadcast
        f32x2 v;
        v[0] = ((id >> 1) == tid && (id & 1) == 0) ? 1.f : 0.f;
        v[1] = ((id >> 1) == tid && (id & 1) == 1) ? 1.f : 0.f;
        enc2[(size_t)(n0 + i) * 256 + tid] = v;
    }

    // --- quantized + loss: tl = row (32), dg = dim-group (8 dims each) ------
    int tl = tid & 31, dg = tid >> 5;
    int idq = sidx[tl];
    const float4* cq4 = (const float4*)(cb + (size_t)idq * 64 + dg * 8);
    float* qp = out + 1 + (size_t)b * D_ * T_ + (size_t)(dg * 8) * T_ + t0 + tl;

    float lsum = 0.f;
#pragma unroll
    for (int j4 = 0; j4 < 2; ++j4) {
        float4 qv = cq4[j4];
        float qe[4] = {qv.x, qv.y, qv.z, qv.w};
#pragma unroll
        for (int e = 0; e < 4; ++e) {
            int dl = j4 * 4 + e;               // 0..7
            float xv = X[dg * 8 + dl][tl];
            float diff = qe[e] - xv;
            lsum = fmaf(diff, diff, lsum);
            qp[(size_t)dl * T_] = xv + diff;   // straight-through: x + (q - x)
        }
    }
    if (tid < 32) atomicAdd(&hist[sidx[tid]], 1);  // one count per row

#pragma unroll
    for (int off = 32; off > 0; off >>= 1) lsum += __shfl_down(lsum, off);
    __shared__ float wsum[4];
    __shared__ int lastflag;
    if ((tid & 63) == 0) wsum[tid >> 6] = lsum;
    __syncthreads();
    if (tid == 0) {
        double s = (double)wsum[0] + (double)wsum[1] + (double)wsum[2] + (double)wsum[3];
        atomicAdd(loss, s);
        __threadfence();                       // release: hist+loss visible before ticket
        int t = atomicAdd(ticket, 1);
        lastflag = (t == (N_ / 32) - 1);
    }
    __syncthreads();

    // --- last block: finalize loss + perplexity (k6 folded in) --------------
    if (lastflag) {
        int h0 = atomicAdd(&hist[tid], 0);         // atomic reads: device-coherent
        int h1 = atomicAdd(&hist[tid + 256], 0);
        double p0 = (double)h0 / (double)N_;
        double p1 = (double)h1 / (double)N_;
        double lp = p0 * log(p0 + 1e-10) + p1 * log(p1 + 1e-10);
#pragma unroll
        for (int off = 32; off > 0; off >>= 1) lp += __shfl_down(lp, off);
        __shared__ double dsum[4];
        if ((tid & 63) == 0) dsum[tid >> 6] = lp;
        __syncthreads();
        if (tid == 0) {
            double s = dsum[0] + dsum[1] + dsum[2] + dsum[3];
            double L = atomicAdd(loss, 0.0);
            out[1 + Q_] = (float)exp(-s);
            out[0] = (float)(1.25 * L / (double)Q_);
        }
    }
}

extern "C" void kernel_launch(void* const* d_in, const int* in_sizes, int n_in,
                              void* d_out, int out_size, void* d_ws, size_t ws_size,
                              hipStream_t stream) {
    const float* in = (const float*)d_in[0];   // [16, 64, 4096] fp32
    const float* cb = (const float*)d_in[1];   // [512, 64] fp32
    float* out = (float*)d_out;
    char* ws = (char*)d_ws;

    double* loss  = (double*)(ws + WS_LOSS);
    int* ticket   = (int*)(ws + WS_TICKET);
    int* hist     = (int*)(ws + WS_HIST);
    float* ne     = (float*)(ws + WS_NE);
    bf16x8* cbh   = (bf16x8*)(ws + WS_CBH);
    bf16x8* cbl   = (bf16x8*)(ws + WS_CBL);

    f32x2* enc2 = (f32x2*)(out + ENC_OFF);

    k0_init<<<16, 256, 0, stream>>>(cb, ne, hist, loss, ticket, cbh, cbl);
    k_main<<<N_ / 32, 256, 0, stream>>>(in, cb, cbh, cbl, ne, out, enc2, hist, loss, ticket);
}

// Round 6
// 202.483 us; speedup vs baseline: 1.5181x; 1.5181x over previous
//
#include <hip/hip_runtime.h>

#define B_ 16
#define D_ 64
#define T_ 4096
#define K_ 512
#define N_ (B_*T_)        // 65536 vectors
#define Q_ (B_*D_*T_)     // 4194304 quantized elements
#define ENC_OFF ((size_t)(2 + Q_))  // encodings start in d_out

// ws layout (bytes) — ~136 KB
#define WS_LOSS    0        // double
#define WS_HIST    16       // int[512]
#define WS_NE      2064     // float[512]
#define WS_CBH     4608     // bf16x8[32*2*64]  (64 KB) codebook hi frags
#define WS_CBL     70144    // bf16x8[32*2*64]  (64 KB) codebook lo frags

typedef __bf16 bf16x8 __attribute__((ext_vector_type(8)));
typedef float  f32x4  __attribute__((ext_vector_type(4)));
typedef float  f32x2  __attribute__((ext_vector_type(2)));

// ---------------- K0: init + ne + codebook hi/lo B-fragments ----------------
// Grid = 16 blocks x 256 threads.
__global__ __launch_bounds__(256) void k0_init(const float* __restrict__ cb,
                                               float* __restrict__ ne,
                                               int* __restrict__ hist,
                                               double* __restrict__ loss,
                                               bf16x8* __restrict__ cbh,
                                               bf16x8* __restrict__ cbl) {
    int bidx = blockIdx.x, tid = threadIdx.x;

    // ne: 32 codes per block, 8 lanes per code
    {
        int code = bidx * 32 + (tid >> 3), sl = tid & 7;
        float s = 0.f;
#pragma unroll
        for (int j = 0; j < 8; ++j) { float c = cb[code * 64 + sl * 8 + j]; s = fmaf(c, c, s); }
        s += __shfl_xor(s, 1); s += __shfl_xor(s, 2); s += __shfl_xor(s, 4);
        if (sl == 0) ne[code] = s;
    }
    if (bidx == 0) {
        hist[tid] = 0; hist[tid + 256] = 0;
        if (tid == 0) *loss = 0.0;
    }

    // B-frag element (ct,ks,lane,j) = cb[ct*16 + (lane&15)][ks*32 + (lane>>4)*8 + j]
    int e = bidx * 256 + tid;
    int ct = e >> 7, ks = (e >> 6) & 1, lane = e & 63;
    int code  = ct * 16 + (lane & 15);
    int dbase = ks * 32 + ((lane >> 4) << 3);
    bf16x8 h, l;
#pragma unroll
    for (int j = 0; j < 8; ++j) {
        float v = cb[code * 64 + dbase + j];
        __bf16 hv = (__bf16)v;
        __bf16 lv = (__bf16)(v - (float)hv);
        h[j] = hv; l[j] = lv;
    }
    cbh[(ct * 2 + ks) * 64 + lane] = h;
    cbl[(ct * 2 + ks) * 64 + lane] = l;
}

// ---------------- K_MAIN: 32-row blocks, grid 2048, 8 blocks/CU -------------
// R4 diagnosis: latency-bound (MfmaUtil 4%, VALUBusy 7%, HBM 18%, occ 30%).
// R5 lesson: per-block __threadfence() = device-scope L2 writeback, cost
// scales with grid (-37us @1024, -98us @2048 blocks) — REMOVED (separate k6,
// plain device atomics only, proven cheap in R0).
// This round isolates the TLP lever: 2048 blocks = 8/CU = 100% wave cap.
__global__ __launch_bounds__(256, 8) void k_main(const float* __restrict__ in,
                                                 const float* __restrict__ cb,
                                                 const bf16x8* __restrict__ cbh,
                                                 const bf16x8* __restrict__ cbl,
                                                 const float* __restrict__ ne,
                                                 float* __restrict__ out,
                                                 f32x2* __restrict__ enc2,
                                                 int* __restrict__ hist,
                                                 double* __restrict__ loss) {
    __shared__ float X[64][33];      // dim-major: X[d][row_local], 8.4 KB
    __shared__ float ne_s[512];
    __shared__ float smin[2][32];
    __shared__ int   smid[2][32];
    __shared__ int   sidx[32];
    int tid = threadIdx.x;
    int n0 = blockIdx.x * 32;
    int b  = n0 >> 12, t0 = n0 & (T_ - 1);

    { // stage x-tile: 64 dims x 32 rows = 2048 floats; 2 float4 per thread
        int d = tid >> 2, c0 = (tid & 3) * 8;
        const float4* ip = (const float4*)(in + ((size_t)b * 64 + d) * T_ + t0 + c0);
        float4 v0 = ip[0], v1 = ip[1];
        X[d][c0 + 0] = v0.x; X[d][c0 + 1] = v0.y; X[d][c0 + 2] = v0.z; X[d][c0 + 3] = v0.w;
        X[d][c0 + 4] = v1.x; X[d][c0 + 5] = v1.y; X[d][c0 + 6] = v1.z; X[d][c0 + 7] = v1.w;
    }
    ne_s[tid] = ne[tid];
    ne_s[tid + 256] = ne[tid + 256];
    __syncthreads();

    int w = tid >> 6, lane = tid & 63;
    int col = lane & 15, q = lane >> 4;
    int rt = w & 1;          // row-tile (16 rows each)
    int ch = w >> 1;         // codebook half (16 ct tiles each)

    // A-frags for this wave's 16 rows: A[m][k=ks*32+q*8+j] = X[k][rt*16+col]
    bf16x8 Ah[2], Al[2];
#pragma unroll
    for (int ks = 0; ks < 2; ++ks) {
        bf16x8 h, l;
#pragma unroll
        for (int j = 0; j < 8; ++j) {
            float v = X[ks * 32 + q * 8 + j][rt * 16 + col];
            __bf16 hv = (__bf16)v;
            __bf16 lv = (__bf16)(v - (float)hv);
            h[j] = hv; l[j] = lv;
        }
        Ah[ks] = h; Al[ks] = l;
    }

    float m1[4]; int i1[4];
#pragma unroll
    for (int e = 0; e < 4; ++e) { m1[e] = 3.4e38f; i1[e] = 0; }

    for (int c16 = 0; c16 < 16; ++c16) {
        int ct = ch * 16 + c16;
        bf16x8 Bh0 = cbh[(ct * 2 + 0) * 64 + lane];
        bf16x8 Bh1 = cbh[(ct * 2 + 1) * 64 + lane];
        bf16x8 Bl0 = cbl[(ct * 2 + 0) * 64 + lane];
        bf16x8 Bl1 = cbl[(ct * 2 + 1) * 64 + lane];
        float nev = ne_s[ct * 16 + col];
        int code = ct * 16 + col;
        f32x4 acc = {0.f, 0.f, 0.f, 0.f};
        acc = __builtin_amdgcn_mfma_f32_16x16x32_bf16(Ah[0], Bh0, acc, 0, 0, 0);
        acc = __builtin_amdgcn_mfma_f32_16x16x32_bf16(Ah[1], Bh1, acc, 0, 0, 0);
        acc = __builtin_amdgcn_mfma_f32_16x16x32_bf16(Ah[0], Bl0, acc, 0, 0, 0);
        acc = __builtin_amdgcn_mfma_f32_16x16x32_bf16(Al[0], Bh0, acc, 0, 0, 0);
        acc = __builtin_amdgcn_mfma_f32_16x16x32_bf16(Ah[1], Bl1, acc, 0, 0, 0);
        acc = __builtin_amdgcn_mfma_f32_16x16x32_bf16(Al[1], Bh1, acc, 0, 0, 0);
        // lo*lo terms ~2^-32 relative: negligible, dropped
#pragma unroll
        for (int e = 0; e < 4; ++e) {
            float sc = fmaf(-2.f, acc[e], nev);   // ||e||^2 - 2 x.e
            bool lt = sc < m1[e];                 // strict: ties keep lowest code
            i1[e] = lt ? code : i1[e];
            m1[e] = lt ? sc : m1[e];
        }
    }

    // argmin across the 16 lanes (same q) holding this row's columns
#pragma unroll
    for (int e = 0; e < 4; ++e) {
        float a1 = m1[e]; int ai = i1[e];
#pragma unroll
        for (int off = 1; off < 16; off <<= 1) {
            float o1 = __shfl_xor(a1, off);
            int   oi = __shfl_xor(ai, off);
            bool tk = (o1 < a1) || (o1 == a1 && oi < ai);  // tie -> lower index
            a1 = tk ? o1 : a1; ai = tk ? oi : ai;
        }
        if (col == 0) { smin[ch][rt * 16 + q * 4 + e] = a1; smid[ch][rt * 16 + q * 4 + e] = ai; }
    }
    __syncthreads();

    // combine the two codebook halves (ch0 = codes 0..255 wins ties)
    if (tid < 32) {
        float a1 = smin[0][tid]; int ai = smid[0][tid];
        float o1 = smin[1][tid]; int oi = smid[1][tid];
        bool tk = (o1 < a1);                     // strict: tie -> lower code (ch0)
        sidx[tid] = tk ? oi : ai;
    }
    __syncthreads();

    // --- one-hot rows: 256 f32x2 cols per row, 32 rows (cached stores) ------
#pragma unroll 4
    for (int i = 0; i < 32; ++i) {
        int id = sidx[i];                      // uniform LDS read -> broadcast
        f32x2 v;
        v[0] = ((id >> 1) == tid && (id & 1) == 0) ? 1.f : 0.f;
        v[1] = ((id >> 1) == tid && (id & 1) == 1) ? 1.f : 0.f;
        enc2[(size_t)(n0 + i) * 256 + tid] = v;
    }

    // --- quantized + loss: tl = row (32), dg = dim-group (8 dims each) ------
    int tl = tid & 31, dg = tid >> 5;
    int idq = sidx[tl];
    const float4* cq4 = (const float4*)(cb + (size_t)idq * 64 + dg * 8);
    float* qp = out + 1 + (size_t)b * D_ * T_ + (size_t)(dg * 8) * T_ + t0 + tl;

    float lsum = 0.f;
#pragma unroll
    for (int j4 = 0; j4 < 2; ++j4) {
        float4 qv = cq4[j4];
        float qe[4] = {qv.x, qv.y, qv.z, qv.w};
#pragma unroll
        for (int e = 0; e < 4; ++e) {
            int dl = j4 * 4 + e;               // 0..7
            float xv = X[dg * 8 + dl][tl];
            float diff = qe[e] - xv;
            lsum = fmaf(diff, diff, lsum);
            qp[(size_t)dl * T_] = xv + diff;   // straight-through: x + (q - x)
        }
    }
    if (tid < 32) atomicAdd(&hist[sidx[tid]], 1);  // one count per row (device scope, cheap: R0)

#pragma unroll
    for (int off = 32; off > 0; off >>= 1) lsum += __shfl_down(lsum, off);
    __shared__ float wsum[4];
    if ((tid & 63) == 0) wsum[tid >> 6] = lsum;
    __syncthreads();
    if (tid == 0) {
        double s = (double)wsum[0] + (double)wsum[1] + (double)wsum[2] + (double)wsum[3];
        atomicAdd(loss, s);
    }
}

// ---------------- K6: finalize loss + perplexity (trivial, as in R0) --------
__global__ __launch_bounds__(512) void k6_final(const int* __restrict__ hist,
                                                const double* __restrict__ loss,
                                                float* __restrict__ out) {
    __shared__ double sh[512];
    int k = threadIdx.x;
    double p = (double)hist[k] / (double)N_;
    sh[k] = p * log(p + 1e-10);
    __syncthreads();
    for (int s = 256; s > 0; s >>= 1) {
        if (k < s) sh[k] += sh[k + s];
        __syncthreads();
    }
    if (k == 0) {
        out[1 + Q_] = (float)exp(-sh[0]);
        out[0] = (float)(1.25 * (*loss) / (double)Q_);
    }
}

extern "C" void kernel_launch(void* const* d_in, const int* in_sizes, int n_in,
                              void* d_out, int out_size, void* d_ws, size_t ws_size,
                              hipStream_t stream) {
    const float* in = (const float*)d_in[0];   // [16, 64, 4096] fp32
    const float* cb = (const float*)d_in[1];   // [512, 64] fp32
    float* out = (float*)d_out;
    char* ws = (char*)d_ws;

    double* loss  = (double*)(ws + WS_LOSS);
    int* hist     = (int*)(ws + WS_HIST);
    float* ne     = (float*)(ws + WS_NE);
    bf16x8* cbh   = (bf16x8*)(ws + WS_CBH);
    bf16x8* cbl   = (bf16x8*)(ws + WS_CBL);

    f32x2* enc2 = (f32x2*)(out + ENC_OFF);

    k0_init<<<16, 256, 0, stream>>>(cb, ne, hist, loss, cbh, cbl);
    k_main<<<N_ / 32, 256, 0, stream>>>(in, cb, cbh, cbl, ne, out, enc2, hist, loss);
    k6_final<<<1, 512, 0, stream>>>(hist, loss, out);
}